// Round 1
// baseline (1931.128 us; speedup 1.0000x reference)
//
#include <hip/hip_runtime.h>
#include <math.h>

// HungarianLoss: B=128 samples, each a 192x192 LSAP (Jonker-Volgenant
// shortest augmenting path) on cost[q][j] = -softmax(pred[q])[tgt[j]],
// then mean CE with matched classes.
// Decomposition: one 64-lane wave per sample; lane owns columns
// {lane, lane+64, lane+128}. Cost matrix + duals in 150 KiB dynamic LDS.

#define BB 128
#define QQ 192
#define CC 512
#define NBIG 1e30f

__device__ __forceinline__ unsigned long long packmin(float m, int j) {
    // monotonic float->uint key; packed (key<<32)|j so u64-min == argmin
    // with lowest-index tie-break (matches jnp.argmin).
    unsigned u = __float_as_uint(m);
    unsigned key = (u & 0x80000000u) ? ~u : (u | 0x80000000u);
    return ((unsigned long long)key << 32) | (unsigned)j;
}

__launch_bounds__(64)
__global__ void hungarian_kernel(const float* __restrict__ pred,
                                 const int* __restrict__ targets,
                                 float* __restrict__ ws_part) {
    const int b = blockIdx.x;
    const int lane = threadIdx.x;

    extern __shared__ float smem[];
    float* cost  = smem;               // [QQ*QQ]
    float* u_lds = cost + QQ * QQ;     // [QQ] row duals
    float* spc_d = u_lds + QQ;         // [QQ] shortest path costs (dumped)
    float* lse_d = spc_d + QQ;         // [QQ] per-row logsumexp
    int* path_d  = (int*)(lse_d + QQ); // [QQ]
    int* c4r     = path_d + QQ;        // [QQ] col4row
    int* r4c     = c4r + QQ;           // [QQ] row4col
    int* SRd     = r4c + QQ;           // [QQ] scanned-rows flags
    int* tgt     = SRd + QQ;           // [QQ] target classes

    volatile float* uv   = u_lds;
    volatile int* pathv  = path_d;
    volatile int* c4rv   = c4r;
    volatile int* r4cv   = r4c;
    volatile int* SRv    = SRd;

    // ---- init ----
    #pragma unroll
    for (int s = 0; s < 3; s++) {
        int r = lane + 64 * s;
        u_lds[r] = 0.0f;
        c4r[r] = -1;
        r4c[r] = -1;
        SRd[r] = 0;
        tgt[r] = targets[b * QQ + r];
    }
    __syncthreads();

    // ---- fill cost matrix: cost[q][j] = -exp(pred[q][tgt[j]] - lse[q]) ----
    const float* predb = pred + (size_t)b * QQ * CC;
    for (int q = 0; q < QQ; q++) {
        const float* row = predb + (size_t)q * CC;
        float x[8];
        #pragma unroll
        for (int k = 0; k < 8; k++) x[k] = row[lane + 64 * k];
        float mx = x[0];
        #pragma unroll
        for (int k = 1; k < 8; k++) mx = fmaxf(mx, x[k]);
        #pragma unroll
        for (int off = 32; off; off >>= 1) mx = fmaxf(mx, __shfl_xor(mx, off));
        float sum = 0.f;
        #pragma unroll
        for (int k = 0; k < 8; k++) sum += expf(x[k] - mx);
        #pragma unroll
        for (int off = 32; off; off >>= 1) sum += __shfl_xor(sum, off);
        float lse = mx + logf(sum);
        if (lane == 0) lse_d[q] = lse;
        #pragma unroll
        for (int s = 0; s < 3; s++) {
            int j = lane + 64 * s;
            cost[q * QQ + j] = -expf(row[tgt[j]] - lse);
        }
    }
    __syncthreads();

    // ---- JV LSAP: per-column state in registers (3 cols per lane) ----
    float v0 = 0.f, v1 = 0.f, v2 = 0.f;  // column duals

    for (int cur = 0; cur < QQ; cur++) {
        float spc0 = NBIG, spc1 = NBIG, spc2 = NBIG;
        int p0 = 0, p1 = 0, p2 = 0;
        int sc0 = 0, sc1 = 0, sc2 = 0;
        int i = cur;
        float minVal = 0.f;
        int sink = -1;

        while (sink < 0) {
            if (lane == 0) SRv[i] = 1;
            float ui = uv[i];
            const float* crow = cost + i * QQ;
            {
                float r = ((minVal + crow[lane]) - ui) - v0;
                if (!sc0 && r < spc0) { spc0 = r; p0 = i; }
            }
            {
                float r = ((minVal + crow[lane + 64]) - ui) - v1;
                if (!sc1 && r < spc1) { spc1 = r; p1 = i; }
            }
            {
                float r = ((minVal + crow[lane + 128]) - ui) - v2;
                if (!sc2 && r < spc2) { spc2 = r; p2 = i; }
            }
            float m0 = sc0 ? NBIG : spc0;
            float m1 = sc1 ? NBIG : spc1;
            float m2 = sc2 ? NBIG : spc2;

            unsigned long long p = packmin(m0, lane);
            {
                unsigned long long t = packmin(m1, lane + 64);
                if (t < p) p = t;
                t = packmin(m2, lane + 128);
                if (t < p) p = t;
            }
            #pragma unroll
            for (int off = 32; off; off >>= 1) {
                unsigned long long o = __shfl_xor(p, off);
                if (o < p) p = o;
            }
            int jstar = (int)(p & 0xffffffffULL);
            int owner = jstar & 63;
            int slot = jstar >> 6;  // uniform across wave
            float mcur = (slot == 0) ? m0 : ((slot == 1) ? m1 : m2);
            minVal = __shfl(mcur, owner);
            if (slot == 0)      { if (lane == owner) sc0 = 1; }
            else if (slot == 1) { if (lane == owner) sc1 = 1; }
            else                { if (lane == owner) sc2 = 1; }
            int rj = r4cv[jstar];
            if (rj < 0) sink = jstar; else i = rj;
        }

        // dump per-column spc/path for the dual update + augmentation
        spc_d[lane] = spc0; spc_d[lane + 64] = spc1; spc_d[lane + 128] = spc2;
        path_d[lane] = p0;  path_d[lane + 64] = p1;  path_d[lane + 128] = p2;
        __syncthreads();

        // dual updates
        if (lane == 0) u_lds[cur] += minVal;
        #pragma unroll
        for (int s = 0; s < 3; s++) {
            int r = lane + 64 * s;
            if (r != cur && SRd[r]) {
                u_lds[r] += minVal - spc_d[c4r[r]];
            }
            SRd[r] = 0;  // clear for next row's search
        }
        if (sc0) v0 -= (minVal - spc0);
        if (sc1) v1 -= (minVal - spc1);
        if (sc2) v2 -= (minVal - spc2);
        __syncthreads();

        // augment along stored path (wave-uniform serial walk, lane0 writes)
        int j = sink;
        while (true) {
            int ip = pathv[j];
            if (lane == 0) r4cv[j] = ip;
            int nj = c4rv[ip];
            if (lane == 0) c4rv[ip] = j;
            if (ip == cur) break;
            j = nj;
        }
        __syncthreads();
    }

    // ---- per-sample CE partial: sum_q (lse[q] - pred[q][tgt[c4r[q]]]) ----
    float part = 0.f;
    #pragma unroll
    for (int s = 0; s < 3; s++) {
        int r = lane + 64 * s;
        int cidx = c4r[r];
        int tc = tgt[cidx];
        part += lse_d[r] - predb[(size_t)r * CC + tc];
    }
    #pragma unroll
    for (int off = 32; off; off >>= 1) part += __shfl_xor(part, off);
    if (lane == 0) ws_part[b] = part;
}

__launch_bounds__(64)
__global__ void reduce_kernel(const float* __restrict__ ws_part,
                              float* __restrict__ out) {
    int lane = threadIdx.x;
    float s = ws_part[lane] + ws_part[lane + 64];
    #pragma unroll
    for (int off = 32; off; off >>= 1) s += __shfl_xor(s, off);
    if (lane == 0) out[0] = s / (float)(BB * QQ);
}

extern "C" void kernel_launch(void* const* d_in, const int* in_sizes, int n_in,
                              void* d_out, int out_size, void* d_ws, size_t ws_size,
                              hipStream_t stream) {
    const float* pred = (const float*)d_in[0];
    const int* targets = (const int*)d_in[1];
    float* out = (float*)d_out;
    float* ws = (float*)d_ws;

    const int lds_bytes = (QQ * QQ + 8 * QQ) * (int)sizeof(float);  // 153600 B

    hipLaunchKernelGGL(hungarian_kernel, dim3(BB), dim3(64), lds_bytes, stream,
                       pred, targets, ws);
    hipLaunchKernelGGL(reduce_kernel, dim3(1), dim3(64), 0, stream, ws, out);
}

// Round 2
// 1191.038 us; speedup vs baseline: 1.6214x; 1.6214x over previous
//
#include <hip/hip_runtime.h>
#include <math.h>

// HungarianLoss: B=128 samples, each a 192x192 LSAP (Jonker-Volgenant
// shortest augmenting path) on cost[q][j] = -softmax(pred[q])[tgt[j]],
// then mean CE with matched classes.
//
// One 64-lane wave per sample; lane owns columns/rows {lane, lane+64, lane+128}.
// ALL solver state in registers (distributed across lanes); uniform-index
// gathers via v_readlane; wave min/max/sum via DPP (row_shr + row_bcast).
// Only the 144KB cost matrix (read-only after fill) + tiny scratch in LDS.

#define BB 128
#define QQ 192
#define CC 512
#define NBIG 1e30f

template<int CTRL>
__device__ __forceinline__ int dpp_mov(int x) {
    return __builtin_amdgcn_update_dpp(x, x, CTRL, 0xf, 0xf, false);
}

// min across 64 lanes; result uniform (via lane 63). Exact (no rounding).
__device__ __forceinline__ float wave_min64(float x) {
    x = fminf(x, __int_as_float(dpp_mov<0x111>(__float_as_int(x))));  // row_shr:1
    x = fminf(x, __int_as_float(dpp_mov<0x112>(__float_as_int(x))));  // row_shr:2
    x = fminf(x, __int_as_float(dpp_mov<0x114>(__float_as_int(x))));  // row_shr:4
    x = fminf(x, __int_as_float(dpp_mov<0x118>(__float_as_int(x))));  // row_shr:8
    x = fminf(x, __int_as_float(dpp_mov<0x142>(__float_as_int(x))));  // row_bcast:15
    x = fminf(x, __int_as_float(dpp_mov<0x143>(__float_as_int(x))));  // row_bcast:31
    return __int_as_float(__builtin_amdgcn_readlane(__float_as_int(x), 63));
}

__device__ __forceinline__ float wave_max64(float x) {
    x = fmaxf(x, __int_as_float(dpp_mov<0x111>(__float_as_int(x))));
    x = fmaxf(x, __int_as_float(dpp_mov<0x112>(__float_as_int(x))));
    x = fmaxf(x, __int_as_float(dpp_mov<0x114>(__float_as_int(x))));
    x = fmaxf(x, __int_as_float(dpp_mov<0x118>(__float_as_int(x))));
    x = fmaxf(x, __int_as_float(dpp_mov<0x142>(__float_as_int(x))));
    x = fmaxf(x, __int_as_float(dpp_mov<0x143>(__float_as_int(x))));
    return __int_as_float(__builtin_amdgcn_readlane(__float_as_int(x), 63));
}

__device__ __forceinline__ float wave_sum64(float x) {
    x += __int_as_float(dpp_mov<0x111>(__float_as_int(x)));
    x += __int_as_float(dpp_mov<0x112>(__float_as_int(x)));
    x += __int_as_float(dpp_mov<0x114>(__float_as_int(x)));
    x += __int_as_float(dpp_mov<0x118>(__float_as_int(x)));
    x += __int_as_float(dpp_mov<0x142>(__float_as_int(x)));
    x += __int_as_float(dpp_mov<0x143>(__float_as_int(x)));
    return __int_as_float(__builtin_amdgcn_readlane(__float_as_int(x), 63));
}

__device__ __forceinline__ float readlane_f(float v, int l) {
    return __int_as_float(__builtin_amdgcn_readlane(__float_as_int(v), l));
}
__device__ __forceinline__ int readlane_i(int v, int l) {
    return __builtin_amdgcn_readlane(v, l);
}

__launch_bounds__(64)
__global__ void hungarian_kernel(const float* __restrict__ pred,
                                 const int* __restrict__ targets,
                                 float* __restrict__ ws_part) {
    const int b = blockIdx.x;
    const int lane = threadIdx.x;

    extern __shared__ float smem[];
    float* cost    = smem;                   // [QQ*QQ] read-only after fill
    float* spc_lds = cost + QQ * QQ;         // [QQ] dumped once per row-solve
    float* lse_lds = spc_lds + QQ;           // [QQ]
    int*   tgt_lds = (int*)(lse_lds + QQ);   // [QQ]

    // ---- targets: registers (owner = col&63, slot = col>>6) + LDS copy ----
    const int t0 = targets[b * QQ + lane];
    const int t1 = targets[b * QQ + lane + 64];
    const int t2 = targets[b * QQ + lane + 128];
    tgt_lds[lane] = t0; tgt_lds[lane + 64] = t1; tgt_lds[lane + 128] = t2;

    // ---- fill cost matrix: cost[q][j] = -exp(pred[q][tgt[j]] - lse[q]) ----
    const float* predb = pred + (size_t)b * QQ * CC;
    float x[8];
    #pragma unroll
    for (int k = 0; k < 8; k++) x[k] = predb[lane + 64 * k];

    for (int q = 0; q < QQ; q++) {
        const float* row = predb + (size_t)q * CC;
        // gather target logits (L1-resident: row was just loaded)
        float g0 = row[t0], g1 = row[t1], g2 = row[t2];
        // prefetch next row
        float xn[8];
        if (q + 1 < QQ) {
            const float* nrow = row + CC;
            #pragma unroll
            for (int k = 0; k < 8; k++) xn[k] = nrow[lane + 64 * k];
        }
        float mx = x[0];
        #pragma unroll
        for (int k = 1; k < 8; k++) mx = fmaxf(mx, x[k]);
        mx = wave_max64(mx);
        float s = 0.f;
        #pragma unroll
        for (int k = 0; k < 8; k++) s += expf(x[k] - mx);
        s = wave_sum64(s);
        float lse = mx + logf(s);
        if (lane == 0) lse_lds[q] = lse;
        cost[q * QQ + lane]       = -expf(g0 - lse);
        cost[q * QQ + lane + 64]  = -expf(g1 - lse);
        cost[q * QQ + lane + 128] = -expf(g2 - lse);
        #pragma unroll
        for (int k = 0; k < 8; k++) x[k] = xn[k];
    }
    // single-wave block: in-wave LDS ordering is guaranteed, no barrier needed.

    // ---- JV LSAP: all state in registers, distributed 3/lane ----
    float u0 = 0.f, u1 = 0.f, u2 = 0.f;   // row duals   (row  = lane+64*slot)
    float v0 = 0.f, v1 = 0.f, v2 = 0.f;   // col duals   (col  = lane+64*slot)
    int   c0 = -1, c1 = -1, c2 = -1;      // col4row
    int   r0 = -1, r1 = -1, r2 = -1;      // row4col

    for (int cur = 0; cur < QQ; cur++) {
        float spc0 = NBIG, spc1 = NBIG, spc2 = NBIG;
        int   p0 = 0, p1 = 0, p2 = 0;     // path (predecessor row per col)
        int   sc0 = 0, sc1 = 0, sc2 = 0;  // settled-col flags
        int   sr0 = 0, sr1 = 0, sr2 = 0;  // scanned-row flags
        int   i = cur;
        float minVal = 0.f;
        int   sink = -1;

        while (sink < 0) {
            const int il = i & 63, is = i >> 6;
            // SR[i] = 1 (owner lane)
            if (lane == il) {
                if (is == 0) sr0 = 1; else if (is == 1) sr1 = 1; else sr2 = 1;
            }
            // u[i] via readlane (uniform index)
            const float ui = readlane_f(is == 0 ? u0 : (is == 1 ? u1 : u2), il);
            const float* crow = cost + i * QQ;
            {
                float r = ((minVal + crow[lane]) - ui) - v0;
                if (!sc0 && r < spc0) { spc0 = r; p0 = i; }
            }
            {
                float r = ((minVal + crow[lane + 64]) - ui) - v1;
                if (!sc1 && r < spc1) { spc1 = r; p1 = i; }
            }
            {
                float r = ((minVal + crow[lane + 128]) - ui) - v2;
                if (!sc2 && r < spc2) { spc2 = r; p2 = i; }
            }
            const float m0 = sc0 ? NBIG : spc0;
            const float m1 = sc1 ? NBIG : spc1;
            const float m2 = sc2 ? NBIG : spc2;

            // global min (uniform), then first-index argmin via slot-ordered ballots
            float mloc = fminf(m0, fminf(m1, m2));
            minVal = wave_min64(mloc);
            unsigned long long b0 = __ballot(m0 == minVal);
            unsigned long long b1 = __ballot(m1 == minVal);
            unsigned long long b2 = __ballot(m2 == minVal);
            int jstar;
            if (b0)      jstar = __ffsll(b0) - 1;
            else if (b1) jstar = 64 + __ffsll(b1) - 1;
            else         jstar = 128 + __ffsll(b2) - 1;

            const int ol = jstar & 63, os = jstar >> 6;
            if (lane == ol) {
                if (os == 0) sc0 = 1; else if (os == 1) sc1 = 1; else sc2 = 1;
            }
            const int rj = readlane_i(os == 0 ? r0 : (os == 1 ? r1 : r2), ol);
            if (rj < 0) sink = jstar; else i = rj;
        }

        // ---- dual updates ----
        {   // u[cur] += minVal
            const int cl = cur & 63, cs = cur >> 6;
            if (lane == cl) {
                if (cs == 0) u0 += minVal; else if (cs == 1) u1 += minVal; else u2 += minVal;
            }
        }
        // u[r] += minVal - spc[col4row[r]] for scanned assigned rows (r != cur)
        spc_lds[lane] = spc0; spc_lds[lane + 64] = spc1; spc_lds[lane + 128] = spc2;
        if (sr0 && lane != cur)              u0 += minVal - spc_lds[c0];
        if (sr1 && (lane + 64) != cur)       u1 += minVal - spc_lds[c1];
        if (sr2 && (lane + 128) != cur)      u2 += minVal - spc_lds[c2];
        // v[j] -= minVal - spc[j] for settled cols
        if (sc0) v0 -= (minVal - spc0);
        if (sc1) v1 -= (minVal - spc1);
        if (sc2) v2 -= (minVal - spc2);

        // ---- augment along stored path (uniform serial walk, register state) ----
        int j = sink;
        while (true) {
            const int jl = j & 63, js = j >> 6;
            const int pj = readlane_i(js == 0 ? p0 : (js == 1 ? p1 : p2), jl);
            if (lane == jl) {
                if (js == 0) r0 = pj; else if (js == 1) r1 = pj; else r2 = pj;
            }
            const int pl = pj & 63, ps = pj >> 6;
            const int nj = readlane_i(ps == 0 ? c0 : (ps == 1 ? c1 : c2), pl);
            if (lane == pl) {
                if (ps == 0) c0 = j; else if (ps == 1) c1 = j; else c2 = j;
            }
            if (pj == cur) break;
            j = nj;
        }
    }

    // ---- per-sample CE partial: sum_r (lse[r] - pred[r][tgt[c4r[r]]]) ----
    float part = 0.f;
    {
        int tc0 = tgt_lds[c0], tc1 = tgt_lds[c1], tc2 = tgt_lds[c2];
        part += lse_lds[lane]       - predb[(size_t)lane * CC + tc0];
        part += lse_lds[lane + 64]  - predb[(size_t)(lane + 64) * CC + tc1];
        part += lse_lds[lane + 128] - predb[(size_t)(lane + 128) * CC + tc2];
    }
    part = wave_sum64(part);
    if (lane == 0) ws_part[b] = part;
}

__launch_bounds__(64)
__global__ void reduce_kernel(const float* __restrict__ ws_part,
                              float* __restrict__ out) {
    int lane = threadIdx.x;
    float s = ws_part[lane] + ws_part[lane + 64];
    s = wave_sum64(s);
    if (lane == 0) out[0] = s / (float)(BB * QQ);
}

extern "C" void kernel_launch(void* const* d_in, const int* in_sizes, int n_in,
                              void* d_out, int out_size, void* d_ws, size_t ws_size,
                              hipStream_t stream) {
    const float* pred = (const float*)d_in[0];
    const int* targets = (const int*)d_in[1];
    float* out = (float*)d_out;
    float* ws = (float*)d_ws;

    const int lds_bytes = (QQ * QQ + 3 * QQ) * (int)sizeof(float);  // 149760 B

    hipLaunchKernelGGL(hungarian_kernel, dim3(BB), dim3(64), lds_bytes, stream,
                       pred, targets, ws);
    hipLaunchKernelGGL(reduce_kernel, dim3(1), dim3(64), 0, stream, ws, out);
}